// Round 5
// baseline (1190.784 us; speedup 1.0000x reference)
//
#include <hip/hip_runtime.h>

#define CIN 64
#define ICN 16
#define HH 256
#define WID 256
#define HW (HH*WID)
#define LL 4096          // 64*64 patches
#define KD 784           // 16*49
#define KDP 800          // PV output row stride
#define KQ 832           // i8 QK row stride (784 padded to 64 multiple)
#define NVT 896          // V^T rows (784 padded to 128 multiple)
#define NB 4
#define SPLITK 4
#define KCH (LL/SPLITK)  // 1024

typedef __attribute__((ext_vector_type(8))) short short8;
typedef __attribute__((ext_vector_type(4))) float f32x4;
typedef __attribute__((ext_vector_type(4))) int i32x4;

__device__ __forceinline__ unsigned short f2bf(float x){
  union { float f; unsigned u; } v; v.f = x;
  unsigned r = v.u + 0x7FFF + ((v.u >> 16) & 1);
  return (unsigned short)(r >> 16);
}

// ---------------- conv1x1 (64 -> 16) for G, P, T at once ----------------
__global__ __launch_bounds__(256) void conv1x1_3(
    const float* __restrict__ x,
    const float* __restrict__ Wg, const float* __restrict__ bg,
    const float* __restrict__ Wp, const float* __restrict__ bp,
    const float* __restrict__ Wt, const float* __restrict__ bt,
    float* __restrict__ G, float* __restrict__ P, float* __restrict__ T) {
  __shared__ float wg[ICN*CIN], wp[ICN*CIN], wt[ICN*CIN];
  int t = threadIdx.x;
  for (int i = t; i < ICN*CIN; i += 256) { wg[i]=Wg[i]; wp[i]=Wp[i]; wt[i]=Wt[i]; }
  __syncthreads();
  int p = blockIdx.x*256 + t;
  float aG[ICN], aP[ICN], aT[ICN];
#pragma unroll
  for (int o=0;o<ICN;o++){ aG[o]=bg[o]; aP[o]=bp[o]; aT[o]=bt[o]; }
  for (int c=0;c<CIN;c++){
    float xv = x[c*HW + p];
#pragma unroll
    for (int o=0;o<ICN;o++){
      aG[o] = fmaf(wg[o*CIN+c], xv, aG[o]);
      aP[o] = fmaf(wp[o*CIN+c], xv, aP[o]);
      aT[o] = fmaf(wt[o*CIN+c], xv, aT[o]);
    }
  }
#pragma unroll
  for (int o=0;o<ICN;o++){ G[o*HW+p]=aG[o]; P[o*HW+p]=aP[o]; T[o*HW+p]=aT[o]; }
}

// ---------------- unfold Q (from G) and K (from P), 2-plane i8 quantized ----------------
__global__ __launch_bounds__(256) void unfold_qk_q(
    const float* __restrict__ G, const float* __restrict__ P,
    char* __restrict__ Q0, char* __restrict__ Q1,
    char* __restrict__ K0, char* __restrict__ K1,
    float* __restrict__ sQ, float* __restrict__ sK){
  __shared__ float gb[KQ], pb[KQ];
  __shared__ float redg[256], redp[256];
  int row = blockIdx.x;
  int iy = row >> 6, ix = row & 63;
  int t = threadIdx.x;
  float gmax = 0.f, pmax = 0.f;
  for (int col = t; col < KQ; col += 256){
    float g = 0.f, p = 0.f;
    if (col < KD){
      int c = col / 49; int r = col - c*49; int dy = r / 7; int dx = r - dy*7;
      int y = (iy<<2) + dy - 1, x = (ix<<2) + dx - 1;
      if ((unsigned)y < HH && (unsigned)x < WID){
        int a = c*HW + (y<<8) + x;
        g = G[a]; p = P[a];
      }
    }
    gb[col] = g; pb[col] = p;
    gmax = fmaxf(gmax, fabsf(g)); pmax = fmaxf(pmax, fabsf(p));
  }
  redg[t]=gmax; redp[t]=pmax; __syncthreads();
  for (int s2=128;s2>0;s2>>=1){
    if (t<s2){ redg[t]=fmaxf(redg[t],redg[t+s2]); redp[t]=fmaxf(redp[t],redp[t+s2]); }
    __syncthreads();
  }
  float mg = redg[0], mp = redp[0];
  float rsg = mg > 0.f ? mg*(1.f/127.f) : 1.f;
  float rsp = mp > 0.f ? mp*(1.f/127.f) : 1.f;
  if (t==0){ sQ[row]=rsg; sK[row]=rsp; }
  float ig = 1.f/rsg, ip = 1.f/rsp;
  if (t < KQ/4){
    char q0[4],q1[4],k0[4],k1[4];
#pragma unroll
    for (int u=0;u<4;u++){
      float xg = gb[t*4+u]*ig;
      float a0 = rintf(xg);
      int ia1 = (int)rintf((xg - a0)*256.f);
      ia1 = ia1>127?127:(ia1<-127?-127:ia1);
      q0[u] = (char)(int)a0; q1[u] = (char)ia1;
      float xp = pb[t*4+u]*ip;
      float b0 = rintf(xp);
      int ib1 = (int)rintf((xp - b0)*256.f);
      ib1 = ib1>127?127:(ib1<-127?-127:ib1);
      k0[u] = (char)(int)b0; k1[u] = (char)ib1;
    }
    size_t o = (size_t)row*KQ + t*4;
    *(char4*)(Q0+o) = make_char4(q0[0],q0[1],q0[2],q0[3]);
    *(char4*)(Q1+o) = make_char4(q1[0],q1[1],q1[2],q1[3]);
    *(char4*)(K0+o) = make_char4(k0[0],k0[1],k0[2],k0[3]);
    *(char4*)(K1+o) = make_char4(k1[0],k1[1],k1[2],k1[3]);
  }
}

// ---------------- unfold V transposed: Vt[col=0..895][row=0..4095] bf16 ----------------
__global__ __launch_bounds__(256) void unfold_vt(
    const float* __restrict__ T, unsigned short* __restrict__ Vt){
  int idx = blockIdx.x*256 + threadIdx.x;    // col*4096 + row
  int col = idx >> 12, row = idx & 4095;
  float t = 0.f;
  if (col < KD){
    int c = col / 49; int r = col - c*49; int dy = r / 7; int dx = r - dy*7;
    int iy = row >> 6, ix = row & 63;
    int y = (iy<<2) + dy - 1, x = (ix<<2) + dx - 1;
    if ((unsigned)y < HH && (unsigned)x < WID) t = T[c*HW + (y<<8) + x];
  }
  Vt[idx] = f2bf(t);
}

// ---------------- QK^T i8 MFMA: logits = 10*rs_i*cs_j*(accH + accC/256) ----------------
__global__ __launch_bounds__(256) void gemm_qk_i8(
    const char* __restrict__ Q0, const char* __restrict__ Q1,
    const char* __restrict__ K0, const char* __restrict__ K1,
    const float* __restrict__ sQ, const float* __restrict__ sK,
    float* __restrict__ ATT){
  __shared__ alignas(16) char lds[4][128*64];   // Q0,Q1,K0,K1 tiles (32 KB)
  const int tid = threadIdx.x;
  const int lane = tid & 63, w = tid >> 6;
  const int wr = w >> 1, wc = w & 1;
  const int row0 = blockIdx.y*128, col0 = blockIdx.x*128;

  const char* base;
  { const char* s0[4] = {
      Q0 + (size_t)row0*KQ, Q1 + (size_t)row0*KQ,
      K0 + (size_t)col0*KQ, K1 + (size_t)col0*KQ };
    base = s0[w]; }

  const int r_lo = lane >> 2, slot = lane & 3;
  int goff[8];
#pragma unroll
  for (int j=0;j<8;j++){
    int r = j*16 + r_lo;
    goff[j] = r*KQ + ((slot ^ ((r>>1)&3))<<4);
  }

  const int lrow = lane & 15, g = lane >> 4;
  int offA[4], offB[4];
#pragma unroll
  for (int i=0;i<4;i++){
    int rA = wr*64 + i*16 + lrow;
    offA[i] = rA*64 + ((g ^ ((rA>>1)&3))<<4);
    int rB = wc*64 + i*16 + lrow;
    offB[i] = rB*64 + ((g ^ ((rB>>1)&3))<<4);
  }

  i32x4 accH[4][4] = {};
  i32x4 accC[4][4] = {};

  for (int kb = 0; kb < KQ; kb += 64){
#pragma unroll
    for (int j=0;j<8;j++)
      __builtin_amdgcn_global_load_lds(
        (const __attribute__((address_space(1))) void*)(base + goff[j] + kb),
        (__attribute__((address_space(3))) void*)(&lds[w][j*1024]), 16, 0, 0);
    __syncthreads();
    i32x4 a0[4], a1[4], b0[4], b1[4];
#pragma unroll
    for (int i=0;i<4;i++){
      a0[i] = *(const i32x4*)&lds[0][offA[i]];
      a1[i] = *(const i32x4*)&lds[1][offA[i]];
      b0[i] = *(const i32x4*)&lds[2][offB[i]];
      b1[i] = *(const i32x4*)&lds[3][offB[i]];
    }
#pragma unroll
    for (int i=0;i<4;i++)
#pragma unroll
      for (int j=0;j<4;j++){
        accH[i][j] = __builtin_amdgcn_mfma_i32_16x16x64_i8(a0[i], b0[j], accH[i][j], 0,0,0);
        accC[i][j] = __builtin_amdgcn_mfma_i32_16x16x64_i8(a0[i], b1[j], accC[i][j], 0,0,0);
        accC[i][j] = __builtin_amdgcn_mfma_i32_16x16x64_i8(a1[i], b0[j], accC[i][j], 0,0,0);
      }
    __syncthreads();
  }

#pragma unroll
  for (int j=0;j<4;j++){
    int col = col0 + wc*64 + j*16 + lrow;
    float cs = sK[col]*10.f;
#pragma unroll
    for (int i=0;i<4;i++){
#pragma unroll
      for (int r=0;r<4;r++){
        int row = row0 + wr*64 + i*16 + g*4 + r;
        float rs = sQ[row];
        ATT[(size_t)row*LL + col] =
          rs*cs*((float)accH[i][j][r] + (float)accC[i][j][r]*0.00390625f);
      }
    }
  }
}

// ---------------- row softmax over 4096, fp32 in -> bf16 out (vectorized) ----------------
__global__ __launch_bounds__(256) void softmax_rows(
    const float* __restrict__ ATT, unsigned short* __restrict__ Pb){
  __shared__ float red[256];
  int t = threadIdx.x;
  const float4* r4 = (const float4*)(ATT + (size_t)blockIdx.x * LL);
  ushort4* po = (ushort4*)(Pb + (size_t)blockIdx.x * LL);
  float4 v[4];
  float mx = -3.4e38f;
#pragma unroll
  for (int i=0;i<4;i++){
    v[i] = r4[t + (i<<8)];
    mx = fmaxf(mx, fmaxf(fmaxf(v[i].x, v[i].y), fmaxf(v[i].z, v[i].w)));
  }
  red[t] = mx; __syncthreads();
  for (int s2=128;s2>0;s2>>=1){ if (t<s2) red[t]=fmaxf(red[t],red[t+s2]); __syncthreads(); }
  mx = red[0]; __syncthreads();
  float sum = 0.f;
#pragma unroll
  for (int i=0;i<4;i++){
    v[i].x = __expf(v[i].x-mx); v[i].y = __expf(v[i].y-mx);
    v[i].z = __expf(v[i].z-mx); v[i].w = __expf(v[i].w-mx);
    sum += v[i].x + v[i].y + v[i].z + v[i].w;
  }
  red[t]=sum; __syncthreads();
  for (int s2=128;s2>0;s2>>=1){ if (t<s2) red[t]+=red[t+s2]; __syncthreads(); }
  float inv = 1.0f / red[0];
#pragma unroll
  for (int i=0;i<4;i++){
    ushort4 o;
    o.x = f2bf(v[i].x*inv); o.y = f2bf(v[i].y*inv);
    o.z = f2bf(v[i].z*inv); o.w = f2bf(v[i].w*inv);
    po[t + (i<<8)] = o;
  }
}

// ---------------- PV MFMA split-K: OUTP[z] = Pb[:, z*1024:(z+1)*1024] @ Vt_chunk ----------------
__global__ __launch_bounds__(256) void gemm_pv_mfma(
    const unsigned short* __restrict__ Pb, const unsigned short* __restrict__ Vt,
    float* __restrict__ OUTP){
  __shared__ alignas(16) short ldsA[128*32];
  __shared__ alignas(16) short ldsB[128*32];
  const int tid = threadIdx.x;
  const int lane = tid & 63, w = tid >> 6;
  const int wr = w >> 1, wc = w & 1;
  const int row0 = blockIdx.y*128, col0 = blockIdx.x*128;
  const int z = blockIdx.z;
  float* OUT = OUTP + (size_t)z * LL * KDP;

  const unsigned short* baseA = Pb + (size_t)row0*LL;
  const unsigned short* baseB = Vt + (size_t)col0*LL;
  const int r_lo = lane >> 2, slot = lane & 3;
  int goff0, goff1;
  { int r = w*16 + r_lo;       goff0 = r*LL + ((slot ^ ((r>>1)&3))<<3); }
  { int r = (4+w)*16 + r_lo;   goff1 = r*LL + ((slot ^ ((r>>1)&3))<<3); }

  const int lrow = lane & 15, g = lane >> 4;
  int offA[4], offB[4];
#pragma unroll
  for (int i=0;i<4;i++){
    int rA = wr*64 + i*16 + lrow;
    offA[i] = rA*32 + ((g ^ ((rA>>1)&3))<<3);
    int rB = wc*64 + i*16 + lrow;
    offB[i] = rB*32 + ((g ^ ((rB>>1)&3))<<3);
  }

  f32x4 acc[4][4] = {};

  const int kend = (z+1)*KCH;
  for (int kb = z*KCH; kb < kend; kb += 32){
    __builtin_amdgcn_global_load_lds(
      (const __attribute__((address_space(1))) void*)(baseA + goff0 + kb),
      (__attribute__((address_space(3))) void*)(&ldsA[w*512]), 16, 0, 0);
    __builtin_amdgcn_global_load_lds(
      (const __attribute__((address_space(1))) void*)(baseA + goff1 + kb),
      (__attribute__((address_space(3))) void*)(&ldsA[(4+w)*512]), 16, 0, 0);
    __builtin_amdgcn_global_load_lds(
      (const __attribute__((address_space(1))) void*)(baseB + goff0 + kb),
      (__attribute__((address_space(3))) void*)(&ldsB[w*512]), 16, 0, 0);
    __builtin_amdgcn_global_load_lds(
      (const __attribute__((address_space(1))) void*)(baseB + goff1 + kb),
      (__attribute__((address_space(3))) void*)(&ldsB[(4+w)*512]), 16, 0, 0);
    __syncthreads();
    short8 a[4], b[4];
#pragma unroll
    for (int i=0;i<4;i++){
      a[i] = *(const short8*)&ldsA[offA[i]];
      b[i] = *(const short8*)&ldsB[offB[i]];
    }
#pragma unroll
    for (int i=0;i<4;i++)
#pragma unroll
      for (int j=0;j<4;j++)
        acc[i][j] = __builtin_amdgcn_mfma_f32_16x16x32_bf16(a[i], b[j], acc[i][j], 0,0,0);
    __syncthreads();
  }

#pragma unroll
  for (int i=0;i<4;i++)
#pragma unroll
    for (int j=0;j<4;j++){
      int col = col0 + wc*64 + j*16 + lrow;
      if (col < KD){
#pragma unroll
        for (int r=0;r<4;r++)
          OUT[(size_t)(row0 + wr*64 + i*16 + g*4 + r)*KDP + col] = acc[i][j][r];
      }
    }
}

// ---------------- sum 4 split-K planes in place (into plane 0) ----------------
__global__ __launch_bounds__(256) void pv_reduce(float* __restrict__ P){
  const size_t PL = (size_t)LL*KDP/4;   // float4 per plane
  size_t idx = (size_t)blockIdx.x*256 + threadIdx.x;
  if (idx >= PL) return;
  float4* p = (float4*)P;
  float4 a = p[idx], b = p[idx+PL], c = p[idx+2*PL], d = p[idx+3*PL];
  a.x += b.x + c.x + d.x;
  a.y += b.y + c.y + d.y;
  a.z += b.z + c.z + d.z;
  a.w += b.w + c.w + d.w;
  p[idx] = a;
}

// ---------------- fused fold (pad=3) + mask-divide + conv1x1 + residual ----------------
__global__ __launch_bounds__(256) void fold_final(
    const float* __restrict__ OUT, const float* __restrict__ xin,
    const float* __restrict__ Ww, const float* __restrict__ bw,
    float* __restrict__ out){
  __shared__ float wsh[CIN*ICN];
  __shared__ float bsh[CIN];
  int t = threadIdx.x;
  for (int i=t;i<CIN*ICN;i+=256) wsh[i]=Ww[i];
  if (t<CIN) bsh[t]=bw[t];
  __syncthreads();
  int p = blockIdx.x*256 + t;         // pixel
  int y = p >> 8, x = p & 255;
  int yc = y + 3, xc = x + 3;
  int i0 = (yc-3) >> 2; int i1 = yc >> 2; if (i1 > 63) i1 = 63;
  int j0 = (xc-3) >> 2; int j1 = xc >> 2; if (j1 > 63) j1 = 63;
  float zi[ICN] = {};
  for (int i = i0; i <= i1; i++){
    int dy = yc - (i<<2);
    for (int j = j0; j <= j1; j++){
      int dx = xc - (j<<2);
      const float* bp = &OUT[(size_t)((i<<6)+j)*KDP + dy*7 + dx];
#pragma unroll
      for (int c=0;c<ICN;c++) zi[c] += bp[c*49];
    }
  }
  float inv = 1.0f / (float)((i1-i0+1)*(j1-j0+1));
#pragma unroll
  for (int c=0;c<ICN;c++) zi[c] *= inv;
#pragma unroll
  for (int co=0;co<CIN;co++){
    float acc = xin[co*HW + p] + bsh[co];
    const float4* w4 = (const float4*)&wsh[co*ICN];
#pragma unroll
    for (int c4=0;c4<4;c4++){
      float4 wv = w4[c4];
      acc = fmaf(wv.x, zi[c4*4+0], acc);
      acc = fmaf(wv.y, zi[c4*4+1], acc);
      acc = fmaf(wv.z, zi[c4*4+2], acc);
      acc = fmaf(wv.w, zi[c4*4+3], acc);
    }
    out[co*HW + p] = acc;
  }
}

extern "C" void kernel_launch(void* const* d_in, const int* in_sizes, int n_in,
                              void* d_out, int out_size, void* d_ws, size_t ws_size,
                              hipStream_t stream) {
  const float* xb = (const float*)d_in[0];
  const float* Wg = (const float*)d_in[1];
  const float* bg = (const float*)d_in[2];
  const float* Wt = (const float*)d_in[3];
  const float* bt = (const float*)d_in[4];
  const float* Wp = (const float*)d_in[5];
  const float* bp = (const float*)d_in[6];
  const float* Ww = (const float*)d_in[7];
  const float* bw = (const float*)d_in[8];
  float* out = (float*)d_out;

  char* ws = (char*)d_ws;
  // layout (bytes):
  //  0        G / Pb(alias, dead)        4 MB
  //  4194304  Pc                         4 MB
  //  8388608  T                          4 MB
  //  12582912 Q0,Q1,K0,K1 (3.4MB each)
  //  26214400 sQ, 26230784 sK
  //  33554432 ATT (64MB) / OUTP[4] (52.4MB, alias after softmax); plane0 = final OUT
  //  100663296 Vt (7.34MB)
  float*          G   = (float*)(ws + 0);
  float*          Pc  = (float*)(ws + 4194304);
  float*          T   = (float*)(ws + 8388608);
  char*           Q0  = (char*)(ws + 12582912);
  char*           Q1  = (char*)(ws + 15990784);
  char*           K0  = (char*)(ws + 19398656);
  char*           K1  = (char*)(ws + 22806528);
  float*          sQ  = (float*)(ws + 26214400);
  float*          sK  = (float*)(ws + 26230784);
  float*          ATT = (float*)(ws + 33554432);
  unsigned short* Vt  = (unsigned short*)(ws + 100663296);
  unsigned short* Pb  = (unsigned short*)(ws + 0);
  float*          OUTP= (float*)(ws + 33554432);   // 4 planes, alias ATT (dead)

  for (int b = 0; b < NB; b++){
    const float* x = xb + (size_t)b*CIN*HW;
    conv1x1_3<<<HW/256, 256, 0, stream>>>(x, Wg,bg, Wp,bp, Wt,bt, G,Pc,T);
    unfold_qk_q<<<LL, 256, 0, stream>>>(G, Pc, Q0, Q1, K0, K1, sQ, sK);
    unfold_vt<<<NVT*LL/256, 256, 0, stream>>>(T, Vt);
    gemm_qk_i8<<<dim3(LL/128, LL/128), 256, 0, stream>>>(Q0, Q1, K0, K1, sQ, sK, ATT);
    softmax_rows<<<LL, 256, 0, stream>>>(ATT, Pb);
    gemm_pv_mfma<<<dim3(NVT/128, LL/128, SPLITK), 256, 0, stream>>>(Pb, Vt, OUTP);
    pv_reduce<<<(LL*KDP/4 + 255)/256, 256, 0, stream>>>(OUTP);
    fold_final<<<HW/256, 256, 0, stream>>>(OUTP, x, Ww, bw, out + (size_t)b*CIN*HW);
  }
}

// Round 6
// 1094.147 us; speedup vs baseline: 1.0883x; 1.0883x over previous
//
#include <hip/hip_runtime.h>

#define CIN 64
#define ICN 16
#define HH 256
#define WID 256
#define HW (HH*WID)
#define LL 4096          // 64*64 patches
#define KD 784           // 16*49
#define KDP 800          // PV output row stride
#define KQ 832           // i8 QK row stride (784 padded to 64 multiple)
#define NVT 896          // V^T rows (784 padded to 128 multiple)
#define NB 4
#define SPLITK 4
#define KCH (LL/SPLITK)  // 1024

typedef __attribute__((ext_vector_type(8))) short short8;
typedef __attribute__((ext_vector_type(4))) float f32x4;
typedef __attribute__((ext_vector_type(4))) int i32x4;

__device__ __forceinline__ unsigned short f2bf(float x){
  union { float f; unsigned u; } v; v.f = x;
  unsigned r = v.u + 0x7FFF + ((v.u >> 16) & 1);
  return (unsigned short)(r >> 16);
}

// ---------------- conv1x1 (64 -> 16) for G, P, T at once ----------------
__global__ __launch_bounds__(256) void conv1x1_3(
    const float* __restrict__ x,
    const float* __restrict__ Wg, const float* __restrict__ bg,
    const float* __restrict__ Wp, const float* __restrict__ bp,
    const float* __restrict__ Wt, const float* __restrict__ bt,
    float* __restrict__ G, float* __restrict__ P, float* __restrict__ T) {
  __shared__ float wg[ICN*CIN], wp[ICN*CIN], wt[ICN*CIN];
  int t = threadIdx.x;
  for (int i = t; i < ICN*CIN; i += 256) { wg[i]=Wg[i]; wp[i]=Wp[i]; wt[i]=Wt[i]; }
  __syncthreads();
  int p = blockIdx.x*256 + t;
  float aG[ICN], aP[ICN], aT[ICN];
#pragma unroll
  for (int o=0;o<ICN;o++){ aG[o]=bg[o]; aP[o]=bp[o]; aT[o]=bt[o]; }
  for (int c=0;c<CIN;c++){
    float xv = x[c*HW + p];
#pragma unroll
    for (int o=0;o<ICN;o++){
      aG[o] = fmaf(wg[o*CIN+c], xv, aG[o]);
      aP[o] = fmaf(wp[o*CIN+c], xv, aP[o]);
      aT[o] = fmaf(wt[o*CIN+c], xv, aT[o]);
    }
  }
#pragma unroll
  for (int o=0;o<ICN;o++){ G[o*HW+p]=aG[o]; P[o*HW+p]=aP[o]; T[o*HW+p]=aT[o]; }
}

// ---------------- unfold Q (from G) and K (from P), 2-plane i8 quantized ----------------
__global__ __launch_bounds__(256) void unfold_qk_q(
    const float* __restrict__ G, const float* __restrict__ P,
    char* __restrict__ Q0, char* __restrict__ Q1,
    char* __restrict__ K0, char* __restrict__ K1,
    float* __restrict__ sQ, float* __restrict__ sK){
  __shared__ float gb[KQ], pb[KQ];
  __shared__ float redg[256], redp[256];
  int row = blockIdx.x;
  int iy = row >> 6, ix = row & 63;
  int t = threadIdx.x;
  float gmax = 0.f, pmax = 0.f;
  for (int col = t; col < KQ; col += 256){
    float g = 0.f, p = 0.f;
    if (col < KD){
      int c = col / 49; int r = col - c*49; int dy = r / 7; int dx = r - dy*7;
      int y = (iy<<2) + dy - 1, x = (ix<<2) + dx - 1;
      if ((unsigned)y < HH && (unsigned)x < WID){
        int a = c*HW + (y<<8) + x;
        g = G[a]; p = P[a];
      }
    }
    gb[col] = g; pb[col] = p;
    gmax = fmaxf(gmax, fabsf(g)); pmax = fmaxf(pmax, fabsf(p));
  }
  redg[t]=gmax; redp[t]=pmax; __syncthreads();
  for (int s2=128;s2>0;s2>>=1){
    if (t<s2){ redg[t]=fmaxf(redg[t],redg[t+s2]); redp[t]=fmaxf(redp[t],redp[t+s2]); }
    __syncthreads();
  }
  float mg = redg[0], mp = redp[0];
  float rsg = mg > 0.f ? mg*(1.f/127.f) : 1.f;
  float rsp = mp > 0.f ? mp*(1.f/127.f) : 1.f;
  if (t==0){ sQ[row]=rsg; sK[row]=rsp; }
  float ig = 1.f/rsg, ip = 1.f/rsp;
  if (t < KQ/4){
    char q0[4],q1[4],k0[4],k1[4];
#pragma unroll
    for (int u=0;u<4;u++){
      float xg = gb[t*4+u]*ig;
      float a0 = rintf(xg);
      int ia1 = (int)rintf((xg - a0)*256.f);
      ia1 = ia1>127?127:(ia1<-127?-127:ia1);
      q0[u] = (char)(int)a0; q1[u] = (char)ia1;
      float xp = pb[t*4+u]*ip;
      float b0 = rintf(xp);
      int ib1 = (int)rintf((xp - b0)*256.f);
      ib1 = ib1>127?127:(ib1<-127?-127:ib1);
      k0[u] = (char)(int)b0; k1[u] = (char)ib1;
    }
    size_t o = (size_t)row*KQ + t*4;
    *(char4*)(Q0+o) = make_char4(q0[0],q0[1],q0[2],q0[3]);
    *(char4*)(Q1+o) = make_char4(q1[0],q1[1],q1[2],q1[3]);
    *(char4*)(K0+o) = make_char4(k0[0],k0[1],k0[2],k0[3]);
    *(char4*)(K1+o) = make_char4(k1[0],k1[1],k1[2],k1[3]);
  }
}

// ---------------- unfold V transposed: Vt[col=0..895][row=0..4095] bf16 ----------------
__global__ __launch_bounds__(256) void unfold_vt(
    const float* __restrict__ T, unsigned short* __restrict__ Vt){
  int idx = blockIdx.x*256 + threadIdx.x;    // col*4096 + row
  int col = idx >> 12, row = idx & 4095;
  float t = 0.f;
  if (col < KD){
    int c = col / 49; int r = col - c*49; int dy = r / 7; int dx = r - dy*7;
    int iy = row >> 6, ix = row & 63;
    int y = (iy<<2) + dy - 1, x = (ix<<2) + dx - 1;
    if ((unsigned)y < HH && (unsigned)x < WID) t = T[c*HW + (y<<8) + x];
  }
  Vt[idx] = f2bf(t);
}

// ---------------- QK^T i8 MFMA: 64x64 block, 4 waves of 32x32 ----------------
// occupancy play: acc = 64 VGPR/lane -> ~5 waves/SIMD; 16KB LDS -> ~5 blocks/CU
__global__ __launch_bounds__(256) void gemm_qk_i8(
    const char* __restrict__ Q0, const char* __restrict__ Q1,
    const char* __restrict__ K0, const char* __restrict__ K1,
    const float* __restrict__ sQ, const float* __restrict__ sK,
    float* __restrict__ ATT){
  __shared__ alignas(16) char lds[4][64*64];   // Q0,Q1,K0,K1 tiles (16 KB)
  const int tid = threadIdx.x;
  const int lane = tid & 63, w = tid >> 6;
  const int wr = w >> 1, wc = w & 1;
  // bijective XCD swizzle over 64x64 grid (bx fast within chunk -> shared Q panel)
  int flat = blockIdx.y * 64 + blockIdx.x;
  int nf = (flat & 7) * 512 + (flat >> 3);
  const int row0 = (nf >> 6) * 64, col0 = (nf & 63) * 64;

  const char* base;
  { const char* s0[4] = {
      Q0 + (size_t)row0*KQ, Q1 + (size_t)row0*KQ,
      K0 + (size_t)col0*KQ, K1 + (size_t)col0*KQ };
    base = s0[w]; }

  // staging: wave w fills tile w (64 rows x 64B), 4 loads of 16 rows.
  const int r_lo = lane >> 2, slot = lane & 3;
  int goff[4];
#pragma unroll
  for (int j=0;j<4;j++){
    int r = j*16 + r_lo;
    goff[j] = r*KQ + ((slot ^ ((r>>1)&3))<<4);
  }

  // fragment reads (bytes): row r, k-group g -> r*64 + (g^((r>>1)&3))*16
  const int lrow = lane & 15, g = lane >> 4;
  int offA[2], offB[2];
#pragma unroll
  for (int i=0;i<2;i++){
    int rA = wr*32 + i*16 + lrow;
    offA[i] = rA*64 + ((g ^ ((rA>>1)&3))<<4);
    int rB = wc*32 + i*16 + lrow;
    offB[i] = rB*64 + ((g ^ ((rB>>1)&3))<<4);
  }

  i32x4 accH[2][2] = {};
  i32x4 accC[2][2] = {};

  for (int kb = 0; kb < KQ; kb += 64){
#pragma unroll
    for (int j=0;j<4;j++)
      __builtin_amdgcn_global_load_lds(
        (const __attribute__((address_space(1))) void*)(base + goff[j] + kb),
        (__attribute__((address_space(3))) void*)(&lds[w][j*1024]), 16, 0, 0);
    __syncthreads();
    i32x4 a0[2], a1[2], b0[2], b1[2];
#pragma unroll
    for (int i=0;i<2;i++){
      a0[i] = *(const i32x4*)&lds[0][offA[i]];
      a1[i] = *(const i32x4*)&lds[1][offA[i]];
      b0[i] = *(const i32x4*)&lds[2][offB[i]];
      b1[i] = *(const i32x4*)&lds[3][offB[i]];
    }
#pragma unroll
    for (int i=0;i<2;i++)
#pragma unroll
      for (int j=0;j<2;j++){
        accH[i][j] = __builtin_amdgcn_mfma_i32_16x16x64_i8(a0[i], b0[j], accH[i][j], 0,0,0);
        accC[i][j] = __builtin_amdgcn_mfma_i32_16x16x64_i8(a0[i], b1[j], accC[i][j], 0,0,0);
        accC[i][j] = __builtin_amdgcn_mfma_i32_16x16x64_i8(a1[i], b0[j], accC[i][j], 0,0,0);
      }
    __syncthreads();
  }

#pragma unroll
  for (int j=0;j<2;j++){
    int col = col0 + wc*32 + j*16 + lrow;
    float cs = sK[col]*10.f;
#pragma unroll
    for (int i=0;i<2;i++){
#pragma unroll
      for (int r=0;r<4;r++){
        int row = row0 + wr*32 + i*16 + g*4 + r;
        float rs = sQ[row];
        ATT[(size_t)row*LL + col] =
          rs*cs*((float)accH[i][j][r] + (float)accC[i][j][r]*0.00390625f);
      }
    }
  }
}

// ---------------- row softmax over 4096, fp32 in -> bf16 out (vectorized) ----------------
__global__ __launch_bounds__(256) void softmax_rows(
    const float* __restrict__ ATT, unsigned short* __restrict__ Pb){
  __shared__ float red[256];
  int t = threadIdx.x;
  const float4* r4 = (const float4*)(ATT + (size_t)blockIdx.x * LL);
  ushort4* po = (ushort4*)(Pb + (size_t)blockIdx.x * LL);
  float4 v[4];
  float mx = -3.4e38f;
#pragma unroll
  for (int i=0;i<4;i++){
    v[i] = r4[t + (i<<8)];
    mx = fmaxf(mx, fmaxf(fmaxf(v[i].x, v[i].y), fmaxf(v[i].z, v[i].w)));
  }
  red[t] = mx; __syncthreads();
  for (int s2=128;s2>0;s2>>=1){ if (t<s2) red[t]=fmaxf(red[t],red[t+s2]); __syncthreads(); }
  mx = red[0]; __syncthreads();
  float sum = 0.f;
#pragma unroll
  for (int i=0;i<4;i++){
    v[i].x = __expf(v[i].x-mx); v[i].y = __expf(v[i].y-mx);
    v[i].z = __expf(v[i].z-mx); v[i].w = __expf(v[i].w-mx);
    sum += v[i].x + v[i].y + v[i].z + v[i].w;
  }
  red[t]=sum; __syncthreads();
  for (int s2=128;s2>0;s2>>=1){ if (t<s2) red[t]+=red[t+s2]; __syncthreads(); }
  float inv = 1.0f / red[0];
#pragma unroll
  for (int i=0;i<4;i++){
    ushort4 o;
    o.x = f2bf(v[i].x*inv); o.y = f2bf(v[i].y*inv);
    o.z = f2bf(v[i].z*inv); o.w = f2bf(v[i].w*inv);
    po[t + (i<<8)] = o;
  }
}

// ---------------- PV MFMA split-K: 64x64 block, 4 waves of 32x32, BK=64 ----------------
__global__ __launch_bounds__(256) void gemm_pv_mfma(
    const unsigned short* __restrict__ Pb, const unsigned short* __restrict__ Vt,
    float* __restrict__ OUTP){
  __shared__ alignas(16) short ldsA[64*64];   // [64 rows][64 k] bf16, 8KB
  __shared__ alignas(16) short ldsB[64*64];
  const int tid = threadIdx.x;
  const int lane = tid & 63, w = tid >> 6;
  const int wr = w >> 1, wc = w & 1;
  // swizzle 14x64 (bx fast), z untouched
  int flat = blockIdx.y * 14 + blockIdx.x;
  int nf = (flat & 7) * 112 + (flat >> 3);
  const int col0 = (nf % 14) * 64, row0 = (nf / 14) * 64;
  const int z = blockIdx.z;
  float* OUT = OUTP + (size_t)z * LL * KDP;

  const unsigned short* baseA = Pb + (size_t)row0*LL;
  const unsigned short* baseB = Vt + (size_t)col0*LL;

  // staging: rows are 128B = 8 slots of 16B; swizzle slot ^= (r&7).
  // waves 0,1 stage A (4 loads each of 8 rows), waves 2,3 stage B.
  const int r8 = lane >> 3, slot8 = lane & 7;
  int goffs[4];
  const int jj0 = (w & 1) * 4;
#pragma unroll
  for (int j=0;j<4;j++){
    int r = (jj0 + j)*8 + r8;
    goffs[j] = r*LL + ((slot8 ^ (r&7))<<3);   // shorts
  }

  // fragment reads (shorts): row r, k-step s, group g -> r*64 + ((s*4+g)^(r&7))*8
  const int lrow = lane & 15, g = lane >> 4;
  int offA[2][2], offB[2][2];
#pragma unroll
  for (int i=0;i<2;i++){
    int rA = wr*32 + i*16 + lrow;
    int rB = wc*32 + i*16 + lrow;
#pragma unroll
    for (int s=0;s<2;s++){
      offA[i][s] = rA*64 + (((s*4+g) ^ (rA&7))<<3);
      offB[i][s] = rB*64 + (((s*4+g) ^ (rB&7))<<3);
    }
  }

  f32x4 acc[2][2] = {};

  const int kend = (z+1)*KCH;
  for (int kb = z*KCH; kb < kend; kb += 64){
    if (w < 2){
#pragma unroll
      for (int j=0;j<4;j++)
        __builtin_amdgcn_global_load_lds(
          (const __attribute__((address_space(1))) void*)(baseA + goffs[j] + kb),
          (__attribute__((address_space(3))) void*)((char*)ldsA + (jj0+j)*1024), 16, 0, 0);
    } else {
#pragma unroll
      for (int j=0;j<4;j++)
        __builtin_amdgcn_global_load_lds(
          (const __attribute__((address_space(1))) void*)(baseB + goffs[j] + kb),
          (__attribute__((address_space(3))) void*)((char*)ldsB + (jj0+j)*1024), 16, 0, 0);
    }
    __syncthreads();
    short8 a[2][2], b[2][2];
#pragma unroll
    for (int i=0;i<2;i++)
#pragma unroll
      for (int s=0;s<2;s++){
        a[i][s] = *(const short8*)&ldsA[offA[i][s]];
        b[i][s] = *(const short8*)&ldsB[offB[i][s]];
      }
#pragma unroll
    for (int s=0;s<2;s++)
#pragma unroll
      for (int i=0;i<2;i++)
#pragma unroll
        for (int j=0;j<2;j++)
          acc[i][j] = __builtin_amdgcn_mfma_f32_16x16x32_bf16(a[i][s], b[j][s], acc[i][j], 0,0,0);
    __syncthreads();
  }

#pragma unroll
  for (int i=0;i<2;i++)
#pragma unroll
    for (int j=0;j<2;j++){
      int col = col0 + wc*32 + j*16 + lrow;
      if (col < KD){
#pragma unroll
        for (int r=0;r<4;r++)
          OUT[(size_t)(row0 + wr*32 + i*16 + g*4 + r)*KDP + col] = acc[i][j][r];
      }
    }
}

// ---------------- sum 4 split-K planes in place (into plane 0) ----------------
__global__ __launch_bounds__(256) void pv_reduce(float* __restrict__ P){
  const size_t PL = (size_t)LL*KDP/4;   // float4 per plane
  size_t idx = (size_t)blockIdx.x*256 + threadIdx.x;
  if (idx >= PL) return;
  float4* p = (float4*)P;
  float4 a = p[idx], b = p[idx+PL], c = p[idx+2*PL], d = p[idx+3*PL];
  a.x += b.x + c.x + d.x;
  a.y += b.y + c.y + d.y;
  a.z += b.z + c.z + d.z;
  a.w += b.w + c.w + d.w;
  p[idx] = a;
}

// ---------------- fused fold (pad=3) + mask-divide + conv1x1 + residual ----------------
__global__ __launch_bounds__(256) void fold_final(
    const float* __restrict__ OUT, const float* __restrict__ xin,
    const float* __restrict__ Ww, const float* __restrict__ bw,
    float* __restrict__ out){
  __shared__ float wsh[CIN*ICN];
  __shared__ float bsh[CIN];
  int t = threadIdx.x;
  for (int i=t;i<CIN*ICN;i+=256) wsh[i]=Ww[i];
  if (t<CIN) bsh[t]=bw[t];
  __syncthreads();
  int p = blockIdx.x*256 + t;         // pixel
  int y = p >> 8, x = p & 255;
  int yc = y + 3, xc = x + 3;
  int i0 = (yc-3) >> 2; int i1 = yc >> 2; if (i1 > 63) i1 = 63;
  int j0 = (xc-3) >> 2; int j1 = xc >> 2; if (j1 > 63) j1 = 63;
  float zi[ICN] = {};
  for (int i = i0; i <= i1; i++){
    int dy = yc - (i<<2);
    for (int j = j0; j <= j1; j++){
      int dx = xc - (j<<2);
      const float* bp = &OUT[(size_t)((i<<6)+j)*KDP + dy*7 + dx];
#pragma unroll
      for (int c=0;c<ICN;c++) zi[c] += bp[c*49];
    }
  }
  float inv = 1.0f / (float)((i1-i0+1)*(j1-j0+1));
#pragma unroll
  for (int c=0;c<ICN;c++) zi[c] *= inv;
#pragma unroll
  for (int co=0;co<CIN;co++){
    float acc = xin[co*HW + p] + bsh[co];
    const float4* w4 = (const float4*)&wsh[co*ICN];
#pragma unroll
    for (int c4=0;c4<4;c4++){
      float4 wv = w4[c4];
      acc = fmaf(wv.x, zi[c4*4+0], acc);
      acc = fmaf(wv.y, zi[c4*4+1], acc);
      acc = fmaf(wv.z, zi[c4*4+2], acc);
      acc = fmaf(wv.w, zi[c4*4+3], acc);
    }
    out[co*HW + p] = acc;
  }
}

extern "C" void kernel_launch(void* const* d_in, const int* in_sizes, int n_in,
                              void* d_out, int out_size, void* d_ws, size_t ws_size,
                              hipStream_t stream) {
  const float* xb = (const float*)d_in[0];
  const float* Wg = (const float*)d_in[1];
  const float* bg = (const float*)d_in[2];
  const float* Wt = (const float*)d_in[3];
  const float* bt = (const float*)d_in[4];
  const float* Wp = (const float*)d_in[5];
  const float* bp = (const float*)d_in[6];
  const float* Ww = (const float*)d_in[7];
  const float* bw = (const float*)d_in[8];
  float* out = (float*)d_out;

  char* ws = (char*)d_ws;
  float*          G   = (float*)(ws + 0);
  float*          Pc  = (float*)(ws + 4194304);
  float*          T   = (float*)(ws + 8388608);
  char*           Q0  = (char*)(ws + 12582912);
  char*           Q1  = (char*)(ws + 15990784);
  char*           K0  = (char*)(ws + 19398656);
  char*           K1  = (char*)(ws + 22806528);
  float*          sQ  = (float*)(ws + 26214400);
  float*          sK  = (float*)(ws + 26230784);
  float*          ATT = (float*)(ws + 33554432);
  unsigned short* Vt  = (unsigned short*)(ws + 100663296);
  unsigned short* Pb  = (unsigned short*)(ws + 0);
  float*          OUTP= (float*)(ws + 33554432);   // 4 planes, alias ATT (dead)

  for (int b = 0; b < NB; b++){
    const float* x = xb + (size_t)b*CIN*HW;
    conv1x1_3<<<HW/256, 256, 0, stream>>>(x, Wg,bg, Wp,bp, Wt,bt, G,Pc,T);
    unfold_qk_q<<<LL, 256, 0, stream>>>(G, Pc, Q0, Q1, K0, K1, sQ, sK);
    unfold_vt<<<NVT*LL/256, 256, 0, stream>>>(T, Vt);
    gemm_qk_i8<<<dim3(64, 64), 256, 0, stream>>>(Q0, Q1, K0, K1, sQ, sK, ATT);
    softmax_rows<<<LL, 256, 0, stream>>>(ATT, Pb);
    gemm_pv_mfma<<<dim3(14, 64, SPLITK), 256, 0, stream>>>(Pb, Vt, OUTP);
    pv_reduce<<<(LL*KDP/4 + 255)/256, 256, 0, stream>>>(OUTP);
    fold_final<<<HW/256, 256, 0, stream>>>(OUTP, x, Ww, bw, out + (size_t)b*CIN*HW);
  }
}